// Round 6
// baseline (10281.871 us; speedup 1.0000x reference)
//
#include <hip/hip_runtime.h>
#include <cstdint>
#include <cstddef>

// ---------------------------------------------------------------------------
// Trainer_91216515433187: BN + Dense + LSTM encoder (1024 steps) + 35-step
// autoregressive LSTM decoder.
//
// Round 6: consolidation of proven-on-HW elements only.
//   * r1 topology: 32 blocks x 512 thr, 16 tile-pairs (tile=bid&15,
//     half=bid>>4), recurrent weights register-resident f16 MFMA B-frags,
//     fp32 accum (absmax 2.4e-4).
//   * r3 data path: h exchange + flags via inline-asm sc0 sc1 (IC-coherent,
//     no cache-maintenance ops) — proven visible cross-XCD.
//   * r2/r3: local 128-col half of h via LDS parity double-buffer (halves
//     IC read volume).
//   * NEW vs r3: tid0-ONLY flag poll + barrier release (r3's 9.4us/step came
//     from 256 per-wave pollers queueing on one IC line; now 32 pollers,
//     each on its own 64B line), and pulse register-prefetch rotation so the
//     encoder's global load is off the per-step serial chain.
//   * r4/r5's XCD rendezvous is abandoned: two zero-evidence failures on an
//     assumption this harness cannot verify.
// ---------------------------------------------------------------------------

typedef _Float16 h8 __attribute__((ext_vector_type(8)));
typedef float f4 __attribute__((ext_vector_type(4)));

// ws byte offsets
#define WS_FLAGS  0         // 32 slots x 64 B = 2048
#define WS_HBUF   2048      // 2 par x 16 tiles x 16 rows x 256 k f16 = 262144
#define WS_RKT    264192    // 1024 cols x 256 k f16 = 524288
#define WS_WEFF   788480    // 1024 cols x 8 f f16 = 16384
#define WS_WMLP   804864    // 2 e x 256 k f16 = 1024
#define WS_DEFF   805888    // 2 x 1024 f32 = 8192
#define WS_ZB     814080    // 1024 f32
#define WS_DB     818176    // 1024 f32
#define WS_TOTAL  822272

__device__ __forceinline__ float fexp2(float x){
#if __has_builtin(__builtin_amdgcn_exp2f)
  return __builtin_amdgcn_exp2f(x);
#else
  return exp2f(x);
#endif
}
__device__ __forceinline__ float frcp(float x){
#if __has_builtin(__builtin_amdgcn_rcpf)
  return __builtin_amdgcn_rcpf(x);
#else
  return 1.f / x;
#endif
}
__device__ __forceinline__ float sigf(float x){
  return frcp(1.f + fexp2(-1.44269504f * x));
}
__device__ __forceinline__ float tanh_f(float x){
  return 2.f * frcp(1.f + fexp2(-2.88539008f * x)) - 1.f;
}

// ---- IC-coherent (device-scope) accessors: sc0 sc1 bypass L1+L2 -----------
__device__ __forceinline__ h8 ic_load16(const _Float16* p){
  h8 r;
  asm volatile("global_load_dwordx4 %0, %1, off sc0 sc1" : "=v"(r) : "v"(p));
  return r;   // NOT ready until a subsequent s_waitcnt tied to r
}
__device__ __forceinline__ void ic_wait4(h8& a, h8& b, h8& c, h8& d){
  asm volatile("s_waitcnt vmcnt(0)"
               : "+v"(a), "+v"(b), "+v"(c), "+v"(d));
}
__device__ __forceinline__ void ic_store_h16(_Float16* p, unsigned int v){
  asm volatile("global_store_short %0, %1, off sc0 sc1"
               :: "v"(p), "v"(v) : "memory");
}
__device__ __forceinline__ void ic_fence_stores(){
  asm volatile("s_waitcnt vmcnt(0)" ::: "memory");
}
__device__ __forceinline__ void ic_store_flag(int* p, int v){
  asm volatile("global_store_dword %0, %1, off sc0 sc1"
               :: "v"(p), "v"(v) : "memory");
}
__device__ __forceinline__ int ic_load_flag(const int* p){
  int r;
  asm volatile("global_load_dword %0, %1, off sc0 sc1\n\ts_waitcnt vmcnt(0)"
               : "=v"(r) : "v"(p) : "memory");
  return r;
}

__global__ void zero_ws_k(uint32_t* __restrict__ p, int n){
  int i = blockIdx.x * 256 + threadIdx.x;
  if (i < n) p[i] = 0u;
}

// grid 1024 x 256 threads
__global__ void precompute_k(const float* __restrict__ bn_gamma,
                             const float* __restrict__ bn_beta,
                             const float* __restrict__ bn_mean,
                             const float* __restrict__ bn_var,
                             const float* __restrict__ W_pulse,   // (8,256)
                             const float* __restrict__ b_pulse,   // (256)
                             const float* __restrict__ lstm_k,    // (256,1024)
                             const float* __restrict__ lstm_rk,   // (256,1024)
                             const float* __restrict__ lstm_b,    // (1024)
                             const float* __restrict__ W_eis,     // (2,256)
                             const float* __restrict__ b_eis,     // (256)
                             const float* __restrict__ W_mlp,     // (256,2)
                             _Float16* __restrict__ rkT,          // [col][k]
                             _Float16* __restrict__ WeffT,        // [col][f]
                             _Float16* __restrict__ WmlpT,        // [e][k]
                             float* __restrict__ Deff,            // [e][col]
                             float* __restrict__ zbias,
                             float* __restrict__ dbias)
{
  int gid = blockIdx.x * 256 + threadIdx.x;   // 0..262143
  {
    int col = gid >> 8;
    int k   = gid & 255;
    rkT[col * 256 + k] = (_Float16)lstm_rk[k * 1024 + col];
  }
  if (gid < 512) {
    int e = gid >> 8, k = gid & 255;
    WmlpT[e * 256 + k] = (_Float16)W_mlp[k * 2 + e];
  }
  if (gid < 1024) {
    int j = gid;
    float a[8], bv[8];
#pragma unroll
    for (int f = 0; f < 8; ++f) {
      float af = bn_gamma[f] * rsqrtf(bn_var[f] + 1e-3f);
      a[f]  = af;
      bv[f] = bn_beta[f] - bn_mean[f] * af;
    }
    float m[8] = {0,0,0,0,0,0,0,0};
    float d0 = 0.f, d1 = 0.f, zb2 = 0.f, db2 = 0.f;
    for (int k = 0; k < 256; ++k) {
      float lk = lstm_k[k * 1024 + j];
#pragma unroll
      for (int f = 0; f < 8; ++f) m[f] += W_pulse[f * 256 + k] * lk;
      d0  += W_eis[k]       * lk;
      d1  += W_eis[256 + k] * lk;
      zb2 += b_pulse[k] * lk;
      db2 += b_eis[k]   * lk;
    }
    float zb = lstm_b[j] + zb2;
#pragma unroll
    for (int f = 0; f < 8; ++f) {
      zb += bv[f] * m[f];
      WeffT[j * 8 + f] = (_Float16)(a[f] * m[f]);
    }
    zbias[j] = zb;
    dbias[j] = lstm_b[j] + db2;
    Deff[j]        = d0;
    Deff[1024 + j] = d1;
  }
}

// 32 blocks x 512 threads
__global__ __launch_bounds__(512, 2)
void lstm_main_k(const float* __restrict__ pulse,      // (256,1024,8)
                 const float* __restrict__ embed,      // (1,2)
                 const float* __restrict__ b_mlp,      // (2)
                 const float* __restrict__ scale_w,    // (2)
                 const float* __restrict__ scale_b,    // (2)
                 const _Float16* __restrict__ rkT,
                 const _Float16* __restrict__ WeffT,
                 const _Float16* __restrict__ WmlpT,
                 const float* __restrict__ Deff,
                 const float* __restrict__ zbias,
                 const float* __restrict__ dbias,
                 _Float16* __restrict__ hbuf,          // [par][tile][row][k]
                 int* __restrict__ flags,              // [32 slots x 16 ints]
                 float* __restrict__ out)              // (256,35,2)
{
  const int tid  = threadIdx.x;
  const int wave = tid >> 6;
  const int lane = tid & 63;
  const int quad = lane >> 4;
  const int n    = lane & 15;

  const int bid     = blockIdx.x;
  const int tile    = bid & 15;
  const int half_id = bid >> 4;
  const int b0      = tile * 16;
  const int hc0     = half_id * 128 + wave * 16;
  const int col_h   = hc0 + n;
  const int col_loc = wave * 16 + n;                  // local col within half

  int* const my_flag = flags + (tile * 2 + half_id) * 16;
  const int* const pa_flag = flags + (tile * 2 + (half_id ^ 1)) * 16;

  __shared__ _Float16 wm_lds[8 * 64 * 8];             // W_mlp B-frags
  __shared__ float    tok_lds[32];                    // [row][e]
  __shared__ __align__(16) _Float16 hl[2][16 * 136];  // local h [par][row][128+8]

  // Build W_mlp fragment LDS (N padded 2->16 with zeros).
  {
    int s8 = tid >> 6, L = tid & 63;
    int nn = L & 15, kq = L >> 4;
    h8 v;
#pragma unroll
    for (int j = 0; j < 8; ++j) {
      int k = s8 * 32 + kq * 8 + j;
      v[j] = (nn < 2) ? WmlpT[nn * 256 + k] : (_Float16)0.f;
    }
    *reinterpret_cast<h8*>(&wm_lds[(s8 * 64 + L) * 8]) = v;
  }
  // Zero local-h LDS (h_0 = 0), both parities.
  for (int i = tid; i < 2 * 16 * 136; i += 512) hl[0][i] = (_Float16)0.f;

  // Register-resident weight fragments.
  h8 W[4][8];
  h8 Wf[4];
  float zb[4], db[4], D0[4], D1[4];
#pragma unroll
  for (int g = 0; g < 4; ++g) {
    int col = g * 256 + col_h;
    const _Float16* wp = rkT + col * 256 + quad * 8;
#pragma unroll
    for (int s8 = 0; s8 < 8; ++s8)
      W[g][s8] = *reinterpret_cast<const h8*>(wp + s8 * 32);
    if (quad == 0) {
      Wf[g] = *reinterpret_cast<const h8*>(WeffT + col * 8);
    } else {
#pragma unroll
      for (int j = 0; j < 8; ++j) Wf[g][j] = (_Float16)0.f;
    }
    zb[g] = zbias[col];
    db[g] = dbias[col];
    D0[g] = Deff[col];
    D1[g] = Deff[1024 + col];
  }
  const float sw  = (n < 2) ? scale_w[n] : 0.f;
  const float sb_ = (n < 2) ? scale_b[n] : 0.f;
  const float bm  = (n < 2) ? b_mlp[n]   : 0.f;

  f4 c_frag = {0.f, 0.f, 0.f, 0.f};

  __syncthreads();

  const int rhalf = half_id ^ 1;
  const int lloc  = half_id * 4;   // frag index base, local K half
  const int lrem  = rhalf * 4;     // frag index base, remote K half
  const int hrow_rd_rem = (tile * 16 + n) * 256 + rhalf * 128 + quad * 8;
  const int hrow_wr = (tile * 16 + quad * 4) * 256 + col_h;
  const float* prow = pulse + (size_t)(b0 + n) * 1024 * 8;

#define LOAD_REMOTE(rem, parR)                                                \
  {                                                                           \
    const _Float16* rp = hbuf + (parR) * 65536 + hrow_rd_rem;                 \
    rem[0] = ic_load16(rp);                                                   \
    rem[1] = ic_load16(rp + 32);                                              \
    rem[2] = ic_load16(rp + 64);                                              \
    rem[3] = ic_load16(rp + 96);                                              \
  }

#define LOAD_LOCAL(la, parR)                                                  \
  {                                                                           \
    _Pragma("unroll")                                                         \
    for (int s = 0; s < 4; ++s)                                               \
      la[s] = *reinterpret_cast<const h8*>(                                   \
          &hl[parR][n * 136 + quad * 8 + s * 32]);                            \
  }

#define GATES_AND_STORE(parW)                                                 \
  {                                                                           \
    _Float16* hw = hbuf + (parW) * 65536 + hrow_wr;                           \
    _Pragma("unroll")                                                         \
    for (int r = 0; r < 4; ++r) {                                             \
      float iv = sigf(acc[0][r]);                                             \
      float fv = sigf(acc[1][r]);                                             \
      float gv = tanh_f(acc[2][r]);                                           \
      float ov = sigf(acc[3][r]);                                             \
      float cc = fv * c_frag[r] + iv * gv;                                    \
      c_frag[r] = cc;                                                         \
      _Float16 hv = (_Float16)(ov * tanh_f(cc));                              \
      hl[parW][(quad * 4 + r) * 136 + col_loc] = hv;                          \
      unsigned int bits = (unsigned int)__builtin_bit_cast(unsigned short, hv);\
      ic_store_h16(hw + r * 256, bits);                                       \
    }                                                                         \
  }

// tid0-only poller: 32 pollers chip-wide, each on its own 64B line.
#define SYNC_STEP(t)                                                          \
  {                                                                           \
    ic_fence_stores();        /* this wave's sc0sc1 h-stores ack'd at IC */   \
    __syncthreads();          /* all waves' stores ack'd */                   \
    if (tid == 0) {                                                           \
      ic_store_flag(my_flag, (t) + 1);                                        \
      while (ic_load_flag(pa_flag) < (t) + 1) { }                             \
    }                                                                         \
    __syncthreads();                                                          \
  }

  // pulse software prefetch: registers for step t loaded during step t-1
  f4 pc0 = {0,0,0,0}, pc1 = {0,0,0,0};
  if (quad == 0) {
    const f4* pp = reinterpret_cast<const f4*>(prow);
    pc0 = pp[0]; pc1 = pp[1];
  }

  // ---------------- encoder: t = 0..1023 ----------------
  for (int t = 0; t < 1024; ++t) {
    const int parR = t & 1;
    const int parW = parR ^ 1;

    h8 rem[4];
    LOAD_REMOTE(rem, parR)    // IC loads in flight; not touched until ic_wait4
    h8 la[4];
    LOAD_LOCAL(la, parR)

    // prefetch pulse for t+1 (consumed next iteration)
    f4 pn0, pn1;
    if (quad == 0) {
      const f4* pp = reinterpret_cast<const f4*>(prow + (size_t)((t + 1) & 1023) * 8);
      pn0 = pp[0]; pn1 = pp[1];
    }

    // pa from registers (prefetched last iteration) — zero wait
    h8 pa;
#pragma unroll
    for (int j = 0; j < 8; ++j) pa[j] = (_Float16)0.f;
    if (quad == 0) {
      pa[0] = (_Float16)pc0[0]; pa[1] = (_Float16)pc0[1];
      pa[2] = (_Float16)pc0[2]; pa[3] = (_Float16)pc0[3];
      pa[4] = (_Float16)pc1[0]; pa[5] = (_Float16)pc1[1];
      pa[6] = (_Float16)pc1[2]; pa[7] = (_Float16)pc1[3];
    }

    f4 acc[4];
#pragma unroll
    for (int g = 0; g < 4; ++g) {
      acc[g][0] = zb[g]; acc[g][1] = zb[g]; acc[g][2] = zb[g]; acc[g][3] = zb[g];
    }
    // local-half MFMAs first (LDS data, ready early; remote IC loads in flight)
#pragma unroll
    for (int s = 0; s < 4; ++s) {
#pragma unroll
      for (int g = 0; g < 4; ++g)
        acc[g] = __builtin_amdgcn_mfma_f32_16x16x32_f16(la[s], W[g][lloc + s], acc[g], 0, 0, 0);
    }
    // pulse MFMA (register operands)
#pragma unroll
    for (int g = 0; g < 4; ++g)
      acc[g] = __builtin_amdgcn_mfma_f32_16x16x32_f16(pa, Wf[g], acc[g], 0, 0, 0);

    ic_wait4(rem[0], rem[1], rem[2], rem[3]);
#pragma unroll
    for (int s = 0; s < 4; ++s) {
#pragma unroll
      for (int g = 0; g < 4; ++g)
        acc[g] = __builtin_amdgcn_mfma_f32_16x16x32_f16(rem[s], W[g][lrem + s], acc[g], 0, 0, 0);
    }

    GATES_AND_STORE(parW)

    if (quad == 0) { pc0 = pn0; pc1 = pn1; }   // rotate prefetch

    SYNC_STEP(t)
  }

  // ---------------- decoder: 35 steps ----------------
  if (tid < 32) tok_lds[tid] = embed[tid & 1];
  __syncthreads();

  for (int s = 0; s < 35; ++s) {
    const int t = 1024 + s;
    const int parR = t & 1;
    const int parW = parR ^ 1;

    h8 rem[4];
    LOAD_REMOTE(rem, parR)
    h8 la[4];
    LOAD_LOCAL(la, parR)
    ic_wait4(rem[0], rem[1], rem[2], rem[3]);

    h8 ha[8];
#pragma unroll
    for (int q = 0; q < 4; ++q) { ha[lloc + q] = la[q]; ha[lrem + q] = rem[q]; }

    if (s > 0) {
      // pred_{s-1} = h_t @ W_mlp + b_mlp  (wave0 publishes)
      f4 pf; pf[0] = bm; pf[1] = bm; pf[2] = bm; pf[3] = bm;
#pragma unroll
      for (int s8 = 0; s8 < 8; ++s8) {
        h8 wb = *reinterpret_cast<const h8*>(&wm_lds[(s8 * 64 + lane) * 8]);
        pf = __builtin_amdgcn_mfma_f32_16x16x32_f16(ha[s8], wb, pf, 0, 0, 0);
      }
      if (wave == 0 && n < 2) {
#pragma unroll
        for (int r = 0; r < 4; ++r) {
          int row = quad * 4 + r;
          float v = pf[r];
          tok_lds[row * 2 + n] = v;
          if (half_id == 0)
            out[((b0 + row) * 35 + (s - 1)) * 2 + n] = v * sw + sb_;
        }
      }
      __syncthreads();
    }

    float tk0[4], tk1[4];
#pragma unroll
    for (int r = 0; r < 4; ++r) {
      int row = quad * 4 + r;
      tk0[r] = tok_lds[row * 2];
      tk1[r] = tok_lds[row * 2 + 1];
    }
    f4 acc[4];
#pragma unroll
    for (int g = 0; g < 4; ++g) {
#pragma unroll
      for (int r = 0; r < 4; ++r)
        acc[g][r] = db[g] + tk0[r] * D0[g] + tk1[r] * D1[g];
    }
#pragma unroll
    for (int s8 = 0; s8 < 8; ++s8) {
#pragma unroll
      for (int g = 0; g < 4; ++g)
        acc[g] = __builtin_amdgcn_mfma_f32_16x16x32_f16(ha[s8], W[g][s8], acc[g], 0, 0, 0);
    }

    GATES_AND_STORE(parW)
    SYNC_STEP(t)
  }

  // final pred_34 from h_{1059} (parity 1; flag 1059 already confirmed)
  {
    h8 rem[4];
    LOAD_REMOTE(rem, 1)
    h8 la[4];
    LOAD_LOCAL(la, 1)
    ic_wait4(rem[0], rem[1], rem[2], rem[3]);
    h8 ha[8];
#pragma unroll
    for (int q = 0; q < 4; ++q) { ha[lloc + q] = la[q]; ha[lrem + q] = rem[q]; }
    f4 pf; pf[0] = bm; pf[1] = bm; pf[2] = bm; pf[3] = bm;
#pragma unroll
    for (int s8 = 0; s8 < 8; ++s8) {
      h8 wb = *reinterpret_cast<const h8*>(&wm_lds[(s8 * 64 + lane) * 8]);
      pf = __builtin_amdgcn_mfma_f32_16x16x32_f16(ha[s8], wb, pf, 0, 0, 0);
    }
    if (half_id == 0 && wave == 0 && n < 2) {
#pragma unroll
      for (int r = 0; r < 4; ++r) {
        int row = quad * 4 + r;
        out[((b0 + row) * 35 + 34) * 2 + n] = pf[r] * sw + sb_;
      }
    }
  }
#undef LOAD_REMOTE
#undef LOAD_LOCAL
#undef GATES_AND_STORE
#undef SYNC_STEP
}

extern "C" void kernel_launch(void* const* d_in, const int* in_sizes, int n_in,
                              void* d_out, int out_size, void* d_ws, size_t ws_size,
                              hipStream_t stream) {
  const float* pulse    = (const float*)d_in[0];
  const float* bn_gamma = (const float*)d_in[1];
  const float* bn_beta  = (const float*)d_in[2];
  const float* bn_mean  = (const float*)d_in[3];
  const float* bn_var   = (const float*)d_in[4];
  const float* W_pulse  = (const float*)d_in[5];
  const float* b_pulse  = (const float*)d_in[6];
  const float* lstm_k   = (const float*)d_in[7];
  const float* lstm_rk  = (const float*)d_in[8];
  const float* lstm_b   = (const float*)d_in[9];
  const float* embed    = (const float*)d_in[10];
  const float* W_eis    = (const float*)d_in[11];
  const float* b_eis    = (const float*)d_in[12];
  const float* W_mlp    = (const float*)d_in[13];
  const float* b_mlp    = (const float*)d_in[14];
  const float* scale_w  = (const float*)d_in[15];
  const float* scale_b  = (const float*)d_in[16];

  char* ws = (char*)d_ws;
  int*      flags = (int*)(ws + WS_FLAGS);
  _Float16* hbuf  = (_Float16*)(ws + WS_HBUF);
  _Float16* rkT   = (_Float16*)(ws + WS_RKT);
  _Float16* WeffT = (_Float16*)(ws + WS_WEFF);
  _Float16* WmlpT = (_Float16*)(ws + WS_WMLP);
  float*    Deff  = (float*)(ws + WS_DEFF);
  float*    zbias = (float*)(ws + WS_ZB);
  float*    dbias = (float*)(ws + WS_DB);

  // zero flags + h double-buffer: (2048 + 262144)/4 = 66048 words
  zero_ws_k<<<258, 256, 0, stream>>>((uint32_t*)d_ws, 66048);
  precompute_k<<<1024, 256, 0, stream>>>(bn_gamma, bn_beta, bn_mean, bn_var,
                                         W_pulse, b_pulse, lstm_k, lstm_rk, lstm_b,
                                         W_eis, b_eis, W_mlp,
                                         rkT, WeffT, WmlpT, Deff, zbias, dbias);
  lstm_main_k<<<32, 512, 0, stream>>>(pulse, embed, b_mlp, scale_w, scale_b,
                                      rkT, WeffT, WmlpT, Deff, zbias, dbias,
                                      hbuf, flags, (float*)d_out);
}

// Round 8
// 10245.880 us; speedup vs baseline: 1.0035x; 1.0035x over previous
//
#include <hip/hip_runtime.h>
#include <cstdint>
#include <cstddef>

// ---------------------------------------------------------------------------
// Trainer_91216515433187: BN + Dense + LSTM encoder (1024 steps) + 35-step
// autoregressive LSTM decoder.
//
// Round 8: r6 lineage (proven-terminating sc0sc1 IC exchange, 32 blocks,
// register-resident f16 weights, fp32 accum, absmax 2.4e-4) with ONE change:
// COALESCED h publish. r3/r6 published h as 256 scattered 2-byte
// global_store_short sc0sc1 per wave (stride 512B) — device-scope sub-dword
// scattered stores serialize at the coherence point and the pre-barrier
// vmcnt(0) waits for ~8192 tiny acks per block (theory for the 9.5us/step).
// Now: gates write h only to LDS (hl, already needed for the local half);
// after a barrier, all 512 threads store the block's 4KB half-tile as one
// contiguous global_store_dwordx2 sc0sc1 each (512 x 8B, fully coalesced).
// Flag handshake (tid0 store + poll, own 64B line) and remote 16B sc0sc1
// loads unchanged. r4/r5/r7's XCD-pairing branch is abandoned (3x
// zero-evidence failures; cross-XCD sc0 spins can livelock via stale-line
// install-then-hit).
// ---------------------------------------------------------------------------

typedef _Float16 h8 __attribute__((ext_vector_type(8)));
typedef float f4 __attribute__((ext_vector_type(4)));

// ws byte offsets
#define WS_FLAGS  0         // 32 slots x 64 B = 2048
#define WS_HBUF   2048      // 2 par x 16 tiles x 16 rows x 256 k f16 = 262144
#define WS_RKT    264192    // 1024 cols x 256 k f16 = 524288
#define WS_WEFF   788480    // 1024 cols x 8 f f16 = 16384
#define WS_WMLP   804864    // 2 e x 256 k f16 = 1024
#define WS_DEFF   805888    // 2 x 1024 f32 = 8192
#define WS_ZB     814080    // 1024 f32
#define WS_DB     818176    // 1024 f32
#define WS_TOTAL  822272

__device__ __forceinline__ float fexp2(float x){
#if __has_builtin(__builtin_amdgcn_exp2f)
  return __builtin_amdgcn_exp2f(x);
#else
  return exp2f(x);
#endif
}
__device__ __forceinline__ float frcp(float x){
#if __has_builtin(__builtin_amdgcn_rcpf)
  return __builtin_amdgcn_rcpf(x);
#else
  return 1.f / x;
#endif
}
__device__ __forceinline__ float sigf(float x){
  return frcp(1.f + fexp2(-1.44269504f * x));
}
__device__ __forceinline__ float tanh_f(float x){
  return 2.f * frcp(1.f + fexp2(-2.88539008f * x)) - 1.f;
}

// ---- IC-coherent (device-scope) accessors: sc0 sc1 bypass L1+L2 -----------
__device__ __forceinline__ h8 ic_load16(const _Float16* p){
  h8 r;
  asm volatile("global_load_dwordx4 %0, %1, off sc0 sc1" : "=v"(r) : "v"(p));
  return r;   // NOT ready until a subsequent s_waitcnt tied to r
}
__device__ __forceinline__ void ic_wait4(h8& a, h8& b, h8& c, h8& d){
  asm volatile("s_waitcnt vmcnt(0)"
               : "+v"(a), "+v"(b), "+v"(c), "+v"(d));
}
__device__ __forceinline__ void ic_store_b64(void* p, unsigned long long v){
  asm volatile("global_store_dwordx2 %0, %1, off sc0 sc1"
               :: "v"(p), "v"(v) : "memory");
}
__device__ __forceinline__ void ic_fence_stores(){
  asm volatile("s_waitcnt vmcnt(0)" ::: "memory");
}
__device__ __forceinline__ void ic_store_flag(int* p, int v){
  asm volatile("global_store_dword %0, %1, off sc0 sc1"
               :: "v"(p), "v"(v) : "memory");
}
__device__ __forceinline__ int ic_load_flag(const int* p){
  int r;
  asm volatile("global_load_dword %0, %1, off sc0 sc1\n\ts_waitcnt vmcnt(0)"
               : "=v"(r) : "v"(p) : "memory");
  return r;
}

__global__ void zero_ws_k(uint32_t* __restrict__ p, int n){
  int i = blockIdx.x * 256 + threadIdx.x;
  if (i < n) p[i] = 0u;
}

// grid 1024 x 256 threads
__global__ void precompute_k(const float* __restrict__ bn_gamma,
                             const float* __restrict__ bn_beta,
                             const float* __restrict__ bn_mean,
                             const float* __restrict__ bn_var,
                             const float* __restrict__ W_pulse,   // (8,256)
                             const float* __restrict__ b_pulse,   // (256)
                             const float* __restrict__ lstm_k,    // (256,1024)
                             const float* __restrict__ lstm_rk,   // (256,1024)
                             const float* __restrict__ lstm_b,    // (1024)
                             const float* __restrict__ W_eis,     // (2,256)
                             const float* __restrict__ b_eis,     // (256)
                             const float* __restrict__ W_mlp,     // (256,2)
                             _Float16* __restrict__ rkT,          // [col][k]
                             _Float16* __restrict__ WeffT,        // [col][f]
                             _Float16* __restrict__ WmlpT,        // [e][k]
                             float* __restrict__ Deff,            // [e][col]
                             float* __restrict__ zbias,
                             float* __restrict__ dbias)
{
  int gid = blockIdx.x * 256 + threadIdx.x;   // 0..262143
  {
    int col = gid >> 8;
    int k   = gid & 255;
    rkT[col * 256 + k] = (_Float16)lstm_rk[k * 1024 + col];
  }
  if (gid < 512) {
    int e = gid >> 8, k = gid & 255;
    WmlpT[e * 256 + k] = (_Float16)W_mlp[k * 2 + e];
  }
  if (gid < 1024) {
    int j = gid;
    float a[8], bv[8];
#pragma unroll
    for (int f = 0; f < 8; ++f) {
      float af = bn_gamma[f] * rsqrtf(bn_var[f] + 1e-3f);
      a[f]  = af;
      bv[f] = bn_beta[f] - bn_mean[f] * af;
    }
    float m[8] = {0,0,0,0,0,0,0,0};
    float d0 = 0.f, d1 = 0.f, zb2 = 0.f, db2 = 0.f;
    for (int k = 0; k < 256; ++k) {
      float lk = lstm_k[k * 1024 + j];
#pragma unroll
      for (int f = 0; f < 8; ++f) m[f] += W_pulse[f * 256 + k] * lk;
      d0  += W_eis[k]       * lk;
      d1  += W_eis[256 + k] * lk;
      zb2 += b_pulse[k] * lk;
      db2 += b_eis[k]   * lk;
    }
    float zb = lstm_b[j] + zb2;
#pragma unroll
    for (int f = 0; f < 8; ++f) {
      zb += bv[f] * m[f];
      WeffT[j * 8 + f] = (_Float16)(a[f] * m[f]);
    }
    zbias[j] = zb;
    dbias[j] = lstm_b[j] + db2;
    Deff[j]        = d0;
    Deff[1024 + j] = d1;
  }
}

// 32 blocks x 512 threads
__global__ __launch_bounds__(512, 2)
void lstm_main_k(const float* __restrict__ pulse,      // (256,1024,8)
                 const float* __restrict__ embed,      // (1,2)
                 const float* __restrict__ b_mlp,      // (2)
                 const float* __restrict__ scale_w,    // (2)
                 const float* __restrict__ scale_b,    // (2)
                 const _Float16* __restrict__ rkT,
                 const _Float16* __restrict__ WeffT,
                 const _Float16* __restrict__ WmlpT,
                 const float* __restrict__ Deff,
                 const float* __restrict__ zbias,
                 const float* __restrict__ dbias,
                 _Float16* __restrict__ hbuf,          // [par][tile][row][k]
                 int* __restrict__ flags,              // [32 slots x 16 ints]
                 float* __restrict__ out)              // (256,35,2)
{
  const int tid  = threadIdx.x;
  const int wave = tid >> 6;
  const int lane = tid & 63;
  const int quad = lane >> 4;
  const int n    = lane & 15;

  const int bid     = blockIdx.x;
  const int tile    = bid & 15;
  const int half_id = bid >> 4;
  const int b0      = tile * 16;
  const int hc0     = half_id * 128 + wave * 16;
  const int col_h   = hc0 + n;
  const int col_loc = wave * 16 + n;                  // local col within half

  int* const my_flag = flags + (tile * 2 + half_id) * 16;
  const int* const pa_flag = flags + (tile * 2 + (half_id ^ 1)) * 16;

  __shared__ _Float16 wm_lds[8 * 64 * 8];             // W_mlp B-frags
  __shared__ float    tok_lds[32];                    // [row][e]
  __shared__ __align__(16) _Float16 hl[2][16 * 136];  // local h [par][row][128+8]

  // Build W_mlp fragment LDS (N padded 2->16 with zeros).
  {
    int s8 = tid >> 6, L = tid & 63;
    int nn = L & 15, kq = L >> 4;
    h8 v;
#pragma unroll
    for (int j = 0; j < 8; ++j) {
      int k = s8 * 32 + kq * 8 + j;
      v[j] = (nn < 2) ? WmlpT[nn * 256 + k] : (_Float16)0.f;
    }
    *reinterpret_cast<h8*>(&wm_lds[(s8 * 64 + L) * 8]) = v;
  }
  // Zero local-h LDS (h_0 = 0), both parities.
  for (int i = tid; i < 2 * 16 * 136; i += 512) hl[0][i] = (_Float16)0.f;

  // Register-resident weight fragments.
  h8 W[4][8];
  h8 Wf[4];
  float zb[4], db[4], D0[4], D1[4];
#pragma unroll
  for (int g = 0; g < 4; ++g) {
    int col = g * 256 + col_h;
    const _Float16* wp = rkT + col * 256 + quad * 8;
#pragma unroll
    for (int s8 = 0; s8 < 8; ++s8)
      W[g][s8] = *reinterpret_cast<const h8*>(wp + s8 * 32);
    if (quad == 0) {
      Wf[g] = *reinterpret_cast<const h8*>(WeffT + col * 8);
    } else {
#pragma unroll
      for (int j = 0; j < 8; ++j) Wf[g][j] = (_Float16)0.f;
    }
    zb[g] = zbias[col];
    db[g] = dbias[col];
    D0[g] = Deff[col];
    D1[g] = Deff[1024 + col];
  }
  const float sw  = (n < 2) ? scale_w[n] : 0.f;
  const float sb_ = (n < 2) ? scale_b[n] : 0.f;
  const float bm  = (n < 2) ? b_mlp[n]   : 0.f;

  f4 c_frag = {0.f, 0.f, 0.f, 0.f};

  __syncthreads();

  const int rhalf = half_id ^ 1;
  const int lloc  = half_id * 4;   // frag index base, local K half
  const int lrem  = rhalf * 4;     // frag index base, remote K half
  const int hrow_rd_rem = (tile * 16 + n) * 256 + rhalf * 128 + quad * 8;
  const float* prow = pulse + (size_t)(b0 + n) * 1024 * 8;

  // Coalesced-publish mapping: thread tid -> (row, 4-col group) of the 4KB
  // local half-tile. 512 threads x 8B = 4KB contiguous burst.
  const int prow_i = tid >> 5;           // 0..15
  const int pcg_i  = (tid & 31) * 4;     // 0,4,...,124
  const int pub_src = prow_i * 136 + pcg_i;                       // hl offset
  const int pub_dst = (tile * 16 + prow_i) * 256 + half_id * 128 + pcg_i;

#define LOAD_REMOTE(rem, parR)                                                \
  {                                                                           \
    const _Float16* rp = hbuf + (parR) * 65536 + hrow_rd_rem;                 \
    rem[0] = ic_load16(rp);                                                   \
    rem[1] = ic_load16(rp + 32);                                              \
    rem[2] = ic_load16(rp + 64);                                              \
    rem[3] = ic_load16(rp + 96);                                              \
  }

#define LOAD_LOCAL(la, parR)                                                  \
  {                                                                           \
    _Pragma("unroll")                                                         \
    for (int s = 0; s < 4; ++s)                                               \
      la[s] = *reinterpret_cast<const h8*>(                                   \
          &hl[parR][n * 136 + quad * 8 + s * 32]);                            \
  }

// gates -> c update -> h into LDS only (publish is cooperative, below)
#define GATES_LDS(parW)                                                       \
  {                                                                           \
    _Pragma("unroll")                                                         \
    for (int r = 0; r < 4; ++r) {                                             \
      float iv = sigf(acc[0][r]);                                             \
      float fv = sigf(acc[1][r]);                                             \
      float gv = tanh_f(acc[2][r]);                                           \
      float ov = sigf(acc[3][r]);                                             \
      float cc = fv * c_frag[r] + iv * gv;                                    \
      c_frag[r] = cc;                                                         \
      hl[parW][(quad * 4 + r) * 136 + col_loc] = (_Float16)(ov * tanh_f(cc)); \
    }                                                                         \
  }

// coalesced publish (512 x 8B sc0sc1) + tid0 flag handshake
#define PUBLISH_SYNC(parW, t)                                                 \
  {                                                                           \
    __syncthreads();           /* hl[parW] complete across all waves */       \
    {                                                                         \
      unsigned long long pv = *reinterpret_cast<const unsigned long long*>(   \
          &hl[parW][pub_src]);                                                \
      ic_store_b64(hbuf + (parW) * 65536 + pub_dst, pv);                      \
    }                                                                         \
    ic_fence_stores();         /* this wave's publish ack'd at IC */          \
    __syncthreads();           /* all waves' publishes ack'd */               \
    if (tid == 0) {                                                           \
      ic_store_flag(my_flag, (t) + 1);                                        \
      while (ic_load_flag(pa_flag) < (t) + 1) { }                             \
    }                                                                         \
    __syncthreads();                                                          \
  }

  // pulse software prefetch: registers for step t loaded during step t-1
  f4 pc0 = {0,0,0,0}, pc1 = {0,0,0,0};
  if (quad == 0) {
    const f4* pp = reinterpret_cast<const f4*>(prow);
    pc0 = pp[0]; pc1 = pp[1];
  }

  // ---------------- encoder: t = 0..1023 ----------------
  for (int t = 0; t < 1024; ++t) {
    const int parR = t & 1;
    const int parW = parR ^ 1;

    h8 rem[4];
    LOAD_REMOTE(rem, parR)    // IC loads in flight; not touched until ic_wait4
    h8 la[4];
    LOAD_LOCAL(la, parR)

    // prefetch pulse for t+1 (consumed next iteration)
    f4 pn0, pn1;
    if (quad == 0) {
      const f4* pp = reinterpret_cast<const f4*>(prow + (size_t)((t + 1) & 1023) * 8);
      pn0 = pp[0]; pn1 = pp[1];
    }

    // pa from registers (prefetched last iteration) — zero wait
    h8 pa;
#pragma unroll
    for (int j = 0; j < 8; ++j) pa[j] = (_Float16)0.f;
    if (quad == 0) {
      pa[0] = (_Float16)pc0[0]; pa[1] = (_Float16)pc0[1];
      pa[2] = (_Float16)pc0[2]; pa[3] = (_Float16)pc0[3];
      pa[4] = (_Float16)pc1[0]; pa[5] = (_Float16)pc1[1];
      pa[6] = (_Float16)pc1[2]; pa[7] = (_Float16)pc1[3];
    }

    f4 acc[4];
#pragma unroll
    for (int g = 0; g < 4; ++g) {
      acc[g][0] = zb[g]; acc[g][1] = zb[g]; acc[g][2] = zb[g]; acc[g][3] = zb[g];
    }
    // local-half MFMAs first (LDS data; remote IC loads in flight)
#pragma unroll
    for (int s = 0; s < 4; ++s) {
#pragma unroll
      for (int g = 0; g < 4; ++g)
        acc[g] = __builtin_amdgcn_mfma_f32_16x16x32_f16(la[s], W[g][lloc + s], acc[g], 0, 0, 0);
    }
    // pulse MFMA (register operands)
#pragma unroll
    for (int g = 0; g < 4; ++g)
      acc[g] = __builtin_amdgcn_mfma_f32_16x16x32_f16(pa, Wf[g], acc[g], 0, 0, 0);

    ic_wait4(rem[0], rem[1], rem[2], rem[3]);
#pragma unroll
    for (int s = 0; s < 4; ++s) {
#pragma unroll
      for (int g = 0; g < 4; ++g)
        acc[g] = __builtin_amdgcn_mfma_f32_16x16x32_f16(rem[s], W[g][lrem + s], acc[g], 0, 0, 0);
    }

    GATES_LDS(parW)

    if (quad == 0) { pc0 = pn0; pc1 = pn1; }   // rotate prefetch

    PUBLISH_SYNC(parW, t)
  }

  // ---------------- decoder: 35 steps ----------------
  if (tid < 32) tok_lds[tid] = embed[tid & 1];
  __syncthreads();

  for (int s = 0; s < 35; ++s) {
    const int t = 1024 + s;
    const int parR = t & 1;
    const int parW = parR ^ 1;

    h8 rem[4];
    LOAD_REMOTE(rem, parR)
    h8 la[4];
    LOAD_LOCAL(la, parR)
    ic_wait4(rem[0], rem[1], rem[2], rem[3]);

    h8 ha[8];
#pragma unroll
    for (int q = 0; q < 4; ++q) { ha[lloc + q] = la[q]; ha[lrem + q] = rem[q]; }

    if (s > 0) {
      // pred_{s-1} = h_t @ W_mlp + b_mlp  (wave0 publishes)
      f4 pf; pf[0] = bm; pf[1] = bm; pf[2] = bm; pf[3] = bm;
#pragma unroll
      for (int s8 = 0; s8 < 8; ++s8) {
        h8 wb = *reinterpret_cast<const h8*>(&wm_lds[(s8 * 64 + lane) * 8]);
        pf = __builtin_amdgcn_mfma_f32_16x16x32_f16(ha[s8], wb, pf, 0, 0, 0);
      }
      if (wave == 0 && n < 2) {
#pragma unroll
        for (int r = 0; r < 4; ++r) {
          int row = quad * 4 + r;
          float v = pf[r];
          tok_lds[row * 2 + n] = v;
          if (half_id == 0)
            out[((b0 + row) * 35 + (s - 1)) * 2 + n] = v * sw + sb_;
        }
      }
      __syncthreads();
    }

    float tk0[4], tk1[4];
#pragma unroll
    for (int r = 0; r < 4; ++r) {
      int row = quad * 4 + r;
      tk0[r] = tok_lds[row * 2];
      tk1[r] = tok_lds[row * 2 + 1];
    }
    f4 acc[4];
#pragma unroll
    for (int g = 0; g < 4; ++g) {
#pragma unroll
      for (int r = 0; r < 4; ++r)
        acc[g][r] = db[g] + tk0[r] * D0[g] + tk1[r] * D1[g];
    }
#pragma unroll
    for (int s8 = 0; s8 < 8; ++s8) {
#pragma unroll
      for (int g = 0; g < 4; ++g)
        acc[g] = __builtin_amdgcn_mfma_f32_16x16x32_f16(ha[s8], W[g][s8], acc[g], 0, 0, 0);
    }

    GATES_LDS(parW)
    PUBLISH_SYNC(parW, t)
  }

  // final pred_34 from h_{1059} (parity 1; flag 1059 already confirmed)
  {
    h8 rem[4];
    LOAD_REMOTE(rem, 1)
    h8 la[4];
    LOAD_LOCAL(la, 1)
    ic_wait4(rem[0], rem[1], rem[2], rem[3]);
    h8 ha[8];
#pragma unroll
    for (int q = 0; q < 4; ++q) { ha[lloc + q] = la[q]; ha[lrem + q] = rem[q]; }
    f4 pf; pf[0] = bm; pf[1] = bm; pf[2] = bm; pf[3] = bm;
#pragma unroll
    for (int s8 = 0; s8 < 8; ++s8) {
      h8 wb = *reinterpret_cast<const h8*>(&wm_lds[(s8 * 64 + lane) * 8]);
      pf = __builtin_amdgcn_mfma_f32_16x16x32_f16(ha[s8], wb, pf, 0, 0, 0);
    }
    if (half_id == 0 && wave == 0 && n < 2) {
#pragma unroll
      for (int r = 0; r < 4; ++r) {
        int row = quad * 4 + r;
        out[((b0 + row) * 35 + 34) * 2 + n] = pf[r] * sw + sb_;
      }
    }
  }
#undef LOAD_REMOTE
#undef LOAD_LOCAL
#undef GATES_LDS
#undef PUBLISH_SYNC
}

extern "C" void kernel_launch(void* const* d_in, const int* in_sizes, int n_in,
                              void* d_out, int out_size, void* d_ws, size_t ws_size,
                              hipStream_t stream) {
  const float* pulse    = (const float*)d_in[0];
  const float* bn_gamma = (const float*)d_in[1];
  const float* bn_beta  = (const float*)d_in[2];
  const float* bn_mean  = (const float*)d_in[3];
  const float* bn_var   = (const float*)d_in[4];
  const float* W_pulse  = (const float*)d_in[5];
  const float* b_pulse  = (const float*)d_in[6];
  const float* lstm_k   = (const float*)d_in[7];
  const float* lstm_rk  = (const float*)d_in[8];
  const float* lstm_b   = (const float*)d_in[9];
  const float* embed    = (const float*)d_in[10];
  const float* W_eis    = (const float*)d_in[11];
  const float* b_eis    = (const float*)d_in[12];
  const float* W_mlp    = (const float*)d_in[13];
  const float* b_mlp    = (const float*)d_in[14];
  const float* scale_w  = (const float*)d_in[15];
  const float* scale_b  = (const float*)d_in[16];

  char* ws = (char*)d_ws;
  int*      flags = (int*)(ws + WS_FLAGS);
  _Float16* hbuf  = (_Float16*)(ws + WS_HBUF);
  _Float16* rkT   = (_Float16*)(ws + WS_RKT);
  _Float16* WeffT = (_Float16*)(ws + WS_WEFF);
  _Float16* WmlpT = (_Float16*)(ws + WS_WMLP);
  float*    Deff  = (float*)(ws + WS_DEFF);
  float*    zbias = (float*)(ws + WS_ZB);
  float*    dbias = (float*)(ws + WS_DB);

  // zero flags + h double-buffer: (2048 + 262144)/4 = 66048 words
  zero_ws_k<<<258, 256, 0, stream>>>((uint32_t*)d_ws, 66048);
  precompute_k<<<1024, 256, 0, stream>>>(bn_gamma, bn_beta, bn_mean, bn_var,
                                         W_pulse, b_pulse, lstm_k, lstm_rk, lstm_b,
                                         W_eis, b_eis, W_mlp,
                                         rkT, WeffT, WmlpT, Deff, zbias, dbias);
  lstm_main_k<<<32, 512, 0, stream>>>(pulse, embed, b_mlp, scale_w, scale_b,
                                      rkT, WeffT, WmlpT, Deff, zbias, dbias,
                                      hbuf, flags, (float*)d_out);
}

// Round 9
// 6665.639 us; speedup vs baseline: 1.5425x; 1.5371x over previous
//
#include <hip/hip_runtime.h>
#include <cstdint>
#include <cstddef>

// ---------------------------------------------------------------------------
// Trainer_91216515433187: BN + Dense + LSTM encoder (1024 steps) + 35-step
// autoregressive LSTM decoder.
//
// Round 9: ELIMINATE inter-block communication entirely.
// Evidence r1-r8: any per-step cross-block rendezvous costs 3.8us (fence
// protocol) to 9.6us (sc0sc1 UC protocol) per step and total = 1059 x
// sync-period regardless of tile grouping. So: ONE block per batch-tile.
//   * 16 blocks x 512 thr. Block owns 16 rows x ALL 1024 z-cols.
//   * Weights: k in [0,128) register-resident (Wr[8][4] = 128 VGPR/lane,
//     256 KB/block); k in [128,256) STREAMED from L2 each step (256 KB/step;
//     all 16 blocks read the same rkT -> every XCD L2 caches it).
//   * h (16x256 f16) lives in LDS only, parity double-buffered, stride 272
//     f16 (=136 words = 8 mod 32 banks -> 4-way max aliasing on A-frag
//     ds_read_b128). ONE __syncthreads per step. No flags, no hbuf, no
//     fences, no deadlock modes.
//   * Numerics = proven r1 lineage: f16 weights/h, fp32 accum (absmax
//     2.4e-4). Gate order keras i,f,g,o; wave w owns h-cols [w*32,w*32+32),
//     col-tile ct=g*2+sub -> z-col g*256 + w*32 + sub*16 + n, so i,f,g,o for
//     a given h-col are in-lane (c update local).
// ---------------------------------------------------------------------------

typedef _Float16 h8 __attribute__((ext_vector_type(8)));
typedef float f4 __attribute__((ext_vector_type(4)));

// ws byte offsets
#define WS_RKT    0         // 1024 cols x 256 k f16 = 524288
#define WS_WEFF   524288    // 1024 cols x 8 f f16 = 16384
#define WS_WMLP   540672    // 2 e x 256 k f16 = 1024
#define WS_DEFF   541696    // 2 x 1024 f32 = 8192
#define WS_ZB     549888    // 1024 f32 = 4096
#define WS_DB     553984    // 1024 f32 = 4096
#define WS_TOTAL  558080

#define HSTRIDE 272   // f16 elements per h-row in LDS (136 words = 8 mod 32)

__device__ __forceinline__ float fexp2(float x){
#if __has_builtin(__builtin_amdgcn_exp2f)
  return __builtin_amdgcn_exp2f(x);
#else
  return exp2f(x);
#endif
}
__device__ __forceinline__ float frcp(float x){
#if __has_builtin(__builtin_amdgcn_rcpf)
  return __builtin_amdgcn_rcpf(x);
#else
  return 1.f / x;
#endif
}
__device__ __forceinline__ float sigf(float x){
  return frcp(1.f + fexp2(-1.44269504f * x));
}
__device__ __forceinline__ float tanh_f(float x){
  return 2.f * frcp(1.f + fexp2(-2.88539008f * x)) - 1.f;
}

// grid 1024 x 256 threads
__global__ void precompute_k(const float* __restrict__ bn_gamma,
                             const float* __restrict__ bn_beta,
                             const float* __restrict__ bn_mean,
                             const float* __restrict__ bn_var,
                             const float* __restrict__ W_pulse,   // (8,256)
                             const float* __restrict__ b_pulse,   // (256)
                             const float* __restrict__ lstm_k,    // (256,1024)
                             const float* __restrict__ lstm_rk,   // (256,1024)
                             const float* __restrict__ lstm_b,    // (1024)
                             const float* __restrict__ W_eis,     // (2,256)
                             const float* __restrict__ b_eis,     // (256)
                             const float* __restrict__ W_mlp,     // (256,2)
                             _Float16* __restrict__ rkT,          // [col][k]
                             _Float16* __restrict__ WeffT,        // [col][f]
                             _Float16* __restrict__ WmlpT,        // [e][k]
                             float* __restrict__ Deff,            // [e][col]
                             float* __restrict__ zbias,
                             float* __restrict__ dbias)
{
  int gid = blockIdx.x * 256 + threadIdx.x;   // 0..262143
  {
    int col = gid >> 8;
    int k   = gid & 255;
    rkT[col * 256 + k] = (_Float16)lstm_rk[k * 1024 + col];
  }
  if (gid < 512) {
    int e = gid >> 8, k = gid & 255;
    WmlpT[e * 256 + k] = (_Float16)W_mlp[k * 2 + e];
  }
  if (gid < 1024) {
    int j = gid;
    float a[8], bv[8];
#pragma unroll
    for (int f = 0; f < 8; ++f) {
      float af = bn_gamma[f] * rsqrtf(bn_var[f] + 1e-3f);
      a[f]  = af;
      bv[f] = bn_beta[f] - bn_mean[f] * af;
    }
    float m[8] = {0,0,0,0,0,0,0,0};
    float d0 = 0.f, d1 = 0.f, zb2 = 0.f, db2 = 0.f;
    for (int k = 0; k < 256; ++k) {
      float lk = lstm_k[k * 1024 + j];
#pragma unroll
      for (int f = 0; f < 8; ++f) m[f] += W_pulse[f * 256 + k] * lk;
      d0  += W_eis[k]       * lk;
      d1  += W_eis[256 + k] * lk;
      zb2 += b_pulse[k] * lk;
      db2 += b_eis[k]   * lk;
    }
    float zb = lstm_b[j] + zb2;
#pragma unroll
    for (int f = 0; f < 8; ++f) {
      zb += bv[f] * m[f];
      WeffT[j * 8 + f] = (_Float16)(a[f] * m[f]);
    }
    zbias[j] = zb;
    dbias[j] = lstm_b[j] + db2;
    Deff[j]        = d0;
    Deff[1024 + j] = d1;
  }
}

// 16 blocks x 512 threads; block = one batch tile of 16 rows, full hidden.
__global__ __launch_bounds__(512, 2)
void lstm_main_k(const float* __restrict__ pulse,      // (256,1024,8)
                 const float* __restrict__ embed,      // (1,2)
                 const float* __restrict__ b_mlp,      // (2)
                 const float* __restrict__ scale_w,    // (2)
                 const float* __restrict__ scale_b,    // (2)
                 const _Float16* __restrict__ rkT,
                 const _Float16* __restrict__ WeffT,
                 const _Float16* __restrict__ WmlpT,
                 const float* __restrict__ Deff,
                 const float* __restrict__ zbias,
                 const float* __restrict__ dbias,
                 float* __restrict__ out)               // (256,35,2)
{
  const int tid  = threadIdx.x;
  const int wave = tid >> 6;
  const int lane = tid & 63;
  const int quad = lane >> 4;
  const int n    = lane & 15;

  const int tile = blockIdx.x;
  const int b0   = tile * 16;
  const int hc   = wave * 32;          // this wave's h-col base

  __shared__ __align__(16) _Float16 hl[2][16 * HSTRIDE]; // h state, 2 parities
  __shared__ __align__(16) _Float16 wf_lds[1024 * 8];    // Weff frags [col][8]
  __shared__ __align__(16) _Float16 wm_lds[8 * 64 * 8];  // W_mlp B-frags
  __shared__ float zb_lds[1024];
  __shared__ float db_lds[1024];
  __shared__ float D_lds[2048];
  __shared__ float tok_lds[32];

  // ---- stage LDS tables ----
  for (int i = tid; i < 1024; i += 512)
    *reinterpret_cast<h8*>(&wf_lds[i * 8]) =
        *reinterpret_cast<const h8*>(WeffT + i * 8);
  for (int i = tid; i < 1024; i += 512) {
    zb_lds[i] = zbias[i];
    db_lds[i] = dbias[i];
  }
  for (int i = tid; i < 2048; i += 512) D_lds[i] = Deff[i];
  {
    int s8 = tid >> 6, L = tid & 63;
    int nn = L & 15, kq = L >> 4;
    h8 v;
#pragma unroll
    for (int j = 0; j < 8; ++j) {
      int k = s8 * 32 + kq * 8 + j;
      v[j] = (nn < 2) ? WmlpT[nn * 256 + k] : (_Float16)0.f;
    }
    *reinterpret_cast<h8*>(&wm_lds[(s8 * 64 + L) * 8]) = v;
  }
  // h_0 = 0
  for (int i = tid; i < 16 * HSTRIDE; i += 512) hl[0][i] = (_Float16)0.f;

  // ---- register-resident weight half: k in [0,128) ----
  // col(ct) = (ct>>1)*256 + hc + (ct&1)*16 + n  (gate g=ct>>1, sub=ct&1)
  h8 Wr[8][4];
#pragma unroll
  for (int ct = 0; ct < 8; ++ct) {
    const int col = (ct >> 1) * 256 + hc + (ct & 1) * 16 + n;
    const _Float16* wp = rkT + col * 256 + quad * 8;
#pragma unroll
    for (int s = 0; s < 4; ++s)
      Wr[ct][s] = *reinterpret_cast<const h8*>(wp + s * 32);
  }
  const float sw  = (n < 2) ? scale_w[n] : 0.f;
  const float sb_ = (n < 2) ? scale_b[n] : 0.f;
  const float bm  = (n < 2) ? b_mlp[n]   : 0.f;

  float c[8];
#pragma unroll
  for (int i = 0; i < 8; ++i) c[i] = 0.f;

  __syncthreads();

  const float* prow = pulse + (size_t)(b0 + n) * 1024 * 8;  // quad==0 lanes

  // pulse software prefetch rotation
  f4 pc0 = {0,0,0,0}, pc1 = {0,0,0,0};
  if (quad == 0) {
    const f4* pp = reinterpret_cast<const f4*>(prow);
    pc0 = pp[0]; pc1 = pp[1];
  }

#define K_LOOP(acc, hb)                                                       \
  {                                                                           \
    _Pragma("unroll")                                                         \
    for (int s = 0; s < 4; ++s) {                                             \
      h8 ha = *reinterpret_cast<const h8*>((hb) + s * 32);                    \
      _Pragma("unroll")                                                       \
      for (int ct = 0; ct < 8; ++ct)                                          \
        acc[ct] = __builtin_amdgcn_mfma_f32_16x16x32_f16(ha, Wr[ct][s],       \
                                                         acc[ct], 0, 0, 0);  \
    }                                                                         \
    _Pragma("unroll")                                                         \
    for (int s = 4; s < 8; ++s) {                                             \
      h8 Wc[8];                                                               \
      _Pragma("unroll")                                                       \
      for (int ct = 0; ct < 8; ++ct) {                                        \
        const int col = (ct >> 1) * 256 + hc + (ct & 1) * 16 + n;             \
        Wc[ct] = *reinterpret_cast<const h8*>(rkT + col * 256 + s * 32 +      \
                                              quad * 8);                      \
      }                                                                       \
      h8 ha = *reinterpret_cast<const h8*>((hb) + s * 32);                    \
      _Pragma("unroll")                                                       \
      for (int ct = 0; ct < 8; ++ct)                                          \
        acc[ct] = __builtin_amdgcn_mfma_f32_16x16x32_f16(ha, Wc[ct],          \
                                                         acc[ct], 0, 0, 0);  \
    }                                                                         \
  }

#define GATES(parW)                                                           \
  {                                                                           \
    _Float16* hw = &hl[parW][(quad * 4) * HSTRIDE + hc + n];                  \
    _Pragma("unroll")                                                         \
    for (int sub = 0; sub < 2; ++sub) {                                       \
      _Pragma("unroll")                                                       \
      for (int r = 0; r < 4; ++r) {                                           \
        float iv = sigf(acc[0 + sub][r]);                                     \
        float fv = sigf(acc[2 + sub][r]);                                     \
        float gv = tanh_f(acc[4 + sub][r]);                                   \
        float ov = sigf(acc[6 + sub][r]);                                     \
        float cc = fv * c[sub * 4 + r] + iv * gv;                             \
        c[sub * 4 + r] = cc;                                                  \
        hw[r * HSTRIDE + sub * 16] = (_Float16)(ov * tanh_f(cc));             \
      }                                                                       \
    }                                                                         \
  }

  // ---------------- encoder: t = 0..1023 ----------------
  for (int t = 0; t < 1024; ++t) {
    const int parR = t & 1;
    const int parW = parR ^ 1;

    // prefetch pulse t+1
    f4 pn0, pn1;
    if (quad == 0) {
      const f4* pp = reinterpret_cast<const f4*>(prow + (size_t)((t + 1) & 1023) * 8);
      pn0 = pp[0]; pn1 = pp[1];
    }

    // pa from prefetched registers
    h8 pa;
#pragma unroll
    for (int j = 0; j < 8; ++j) pa[j] = (_Float16)0.f;
    if (quad == 0) {
      pa[0] = (_Float16)pc0[0]; pa[1] = (_Float16)pc0[1];
      pa[2] = (_Float16)pc0[2]; pa[3] = (_Float16)pc0[3];
      pa[4] = (_Float16)pc1[0]; pa[5] = (_Float16)pc1[1];
      pa[6] = (_Float16)pc1[2]; pa[7] = (_Float16)pc1[3];
    }

    f4 acc[8];
#pragma unroll
    for (int ct = 0; ct < 8; ++ct) {
      const int col = (ct >> 1) * 256 + hc + (ct & 1) * 16 + n;
      float z = zb_lds[col];
      acc[ct][0] = z; acc[ct][1] = z; acc[ct][2] = z; acc[ct][3] = z;
    }
    // pulse term (A zero for quad!=0 -> wf garbage harmless there)
#pragma unroll
    for (int ct = 0; ct < 8; ++ct) {
      const int col = (ct >> 1) * 256 + hc + (ct & 1) * 16 + n;
      h8 wf = *reinterpret_cast<const h8*>(&wf_lds[col * 8]);
      acc[ct] = __builtin_amdgcn_mfma_f32_16x16x32_f16(pa, wf, acc[ct], 0, 0, 0);
    }

    const _Float16* hb = &hl[parR][n * HSTRIDE + quad * 8];
    K_LOOP(acc, hb)

    GATES(parW)

    if (quad == 0) { pc0 = pn0; pc1 = pn1; }
    __syncthreads();
  }

  // ---------------- decoder: 35 steps ----------------
  if (tid < 32) tok_lds[tid] = embed[tid & 1];
  __syncthreads();

  for (int s = 0; s < 35; ++s) {
    const int t = 1024 + s;
    const int parR = t & 1;
    const int parW = parR ^ 1;

    const _Float16* hb = &hl[parR][n * HSTRIDE + quad * 8];

    if (s > 0) {
      if (wave == 0) {
        // pred_{s-1} = h_t @ W_mlp + b_mlp
        f4 pf; pf[0] = bm; pf[1] = bm; pf[2] = bm; pf[3] = bm;
#pragma unroll
        for (int s8 = 0; s8 < 8; ++s8) {
          h8 ha = *reinterpret_cast<const h8*>(hb + s8 * 32);
          h8 wb = *reinterpret_cast<const h8*>(&wm_lds[(s8 * 64 + lane) * 8]);
          pf = __builtin_amdgcn_mfma_f32_16x16x32_f16(ha, wb, pf, 0, 0, 0);
        }
        if (n < 2) {
#pragma unroll
          for (int r = 0; r < 4; ++r) {
            int row = quad * 4 + r;
            float v = pf[r];
            tok_lds[row * 2 + n] = v;
            out[((b0 + row) * 35 + (s - 1)) * 2 + n] = v * sw + sb_;
          }
        }
      }
      __syncthreads();
    }

    float tk0[4], tk1[4];
#pragma unroll
    for (int r = 0; r < 4; ++r) {
      int row = quad * 4 + r;
      tk0[r] = tok_lds[row * 2];
      tk1[r] = tok_lds[row * 2 + 1];
    }
    f4 acc[8];
#pragma unroll
    for (int ct = 0; ct < 8; ++ct) {
      const int col = (ct >> 1) * 256 + hc + (ct & 1) * 16 + n;
      float db = db_lds[col];
      float d0 = D_lds[col];
      float d1 = D_lds[1024 + col];
#pragma unroll
      for (int r = 0; r < 4; ++r)
        acc[ct][r] = db + tk0[r] * d0 + tk1[r] * d1;
    }

    K_LOOP(acc, hb)

    GATES(parW)
    __syncthreads();
  }

  // final pred_34 from h_{1059} (in hl[1])
  {
    const _Float16* hb = &hl[1][n * HSTRIDE + quad * 8];
    if (wave == 0) {
      f4 pf; pf[0] = bm; pf[1] = bm; pf[2] = bm; pf[3] = bm;
#pragma unroll
      for (int s8 = 0; s8 < 8; ++s8) {
        h8 ha = *reinterpret_cast<const h8*>(hb + s8 * 32);
        h8 wb = *reinterpret_cast<const h8*>(&wm_lds[(s8 * 64 + lane) * 8]);
        pf = __builtin_amdgcn_mfma_f32_16x16x32_f16(ha, wb, pf, 0, 0, 0);
      }
      if (n < 2) {
#pragma unroll
        for (int r = 0; r < 4; ++r) {
          int row = quad * 4 + r;
          out[((b0 + row) * 35 + 34) * 2 + n] = pf[r] * sw + sb_;
        }
      }
    }
  }
#undef K_LOOP
#undef GATES
}

extern "C" void kernel_launch(void* const* d_in, const int* in_sizes, int n_in,
                              void* d_out, int out_size, void* d_ws, size_t ws_size,
                              hipStream_t stream) {
  const float* pulse    = (const float*)d_in[0];
  const float* bn_gamma = (const float*)d_in[1];
  const float* bn_beta  = (const float*)d_in[2];
  const float* bn_mean  = (const float*)d_in[3];
  const float* bn_var   = (const float*)d_in[4];
  const float* W_pulse  = (const float*)d_in[5];
  const float* b_pulse  = (const float*)d_in[6];
  const float* lstm_k   = (const float*)d_in[7];
  const float* lstm_rk  = (const float*)d_in[8];
  const float* lstm_b   = (const float*)d_in[9];
  const float* embed    = (const float*)d_in[10];
  const float* W_eis    = (const float*)d_in[11];
  const float* b_eis    = (const float*)d_in[12];
  const float* W_mlp    = (const float*)d_in[13];
  const float* b_mlp    = (const float*)d_in[14];
  const float* scale_w  = (const float*)d_in[15];
  const float* scale_b  = (const float*)d_in[16];

  char* ws = (char*)d_ws;
  _Float16* rkT   = (_Float16*)(ws + WS_RKT);
  _Float16* WeffT = (_Float16*)(ws + WS_WEFF);
  _Float16* WmlpT = (_Float16*)(ws + WS_WMLP);
  float*    Deff  = (float*)(ws + WS_DEFF);
  float*    zbias = (float*)(ws + WS_ZB);
  float*    dbias = (float*)(ws + WS_DB);

  precompute_k<<<1024, 256, 0, stream>>>(bn_gamma, bn_beta, bn_mean, bn_var,
                                         W_pulse, b_pulse, lstm_k, lstm_rk, lstm_b,
                                         W_eis, b_eis, W_mlp,
                                         rkT, WeffT, WmlpT, Deff, zbias, dbias);
  lstm_main_k<<<16, 512, 0, stream>>>(pulse, embed, b_mlp, scale_w, scale_b,
                                      rkT, WeffT, WmlpT, Deff, zbias, dbias,
                                      (float*)d_out);
}